// Round 6
// baseline (369.839 us; speedup 1.0000x reference)
//
#include <hip/hip_runtime.h>
#include <math.h>

// Problem constants
#define BATCH 32
#define H 512
#define W 512
#define OUTD 502          // 512 - 11 + 1
#define WS 11
#define STRIP 32          // output rows per block
#define INROWS 42         // STRIP + WS - 1 input rows per strip
#define WPAD 80           // per-wave LDS row width in float4 units: 64 + 10 halo + pad

#define C1F 6.5025f       // (0.01*255)^2
#define C2F 58.5225f      // (0.03*255)^2
#define N_OUT_TOTAL 8064128.0   // 32 * 502 * 502

struct GW { float g[WS]; };
struct F3 { float x, y, z; };   // 12-byte RGB pixel load

// ROUND-14: occupancy via the EXACT allocator knob.
// Register-pressure history: minimal live set ~100 regs, but the
// allocator never targets 128 on its own:
//   round 8  (no fence, scalar diet, rolled): 124 VGPR, 121 us  <- lucky
//   round 11 (fence, float4 diet, unrolled):  236 VGPR, 180 us
//   round 12 (launch_bounds(256,4)):           64 VGPR, 424 MB spill, 305 us
//   round 13 (fence, float4 diet, rolled):    224 VGPR, 196 us
// launch_bounds' 2nd arg made the allocator OVERSHOOT (chased the top of
// the waves range -> 64 VGPR + spill). amdgpu_waves_per_eu(4,4) pins
// min=max=4 waves/EU: min drives the budget to 512/4 = 128 VGPR, max
// forbids going lower. One variable changed vs round 13.
// Everything else is the twice-proven-correct round-13 structure:
//   * one compiler fence per ROW_STEP (orders wave-private DS traffic;
//     HW runs DS ops in wave order, fence makes emitted order = program
//     order across steps) — fixed the round-6/7/9/10 race, absmax 0.0.
//   * rolled 2-chunk output loop + 10-row unrolled tail.
//   * float4 LDS payload (a, c, a^2+c^2, a*c): h-conv tap =
//     ds_read_b128 + 4 FMA; squares/cross computed once per column.
//   * luma as 3 FMAs; SSIM divide via v_rcp_f32; f32 accumulator;
//     12-byte RGB struct loads; ring zero-init; 1-row-ahead prefetch.

#define LDS_FENCE() asm volatile("" ::: "memory")

__device__ __forceinline__ float luma3(float r, float g, float b) {
    // y = ((x+1)*127.5) dot w / 256 + 16  ==  x dot W + K, all f32-folded
    constexpr float W0 = 127.5f * 65.738f  / 256.f;
    constexpr float W1 = 127.5f * 129.057f / 256.f;
    constexpr float W2 = 127.5f * 25.064f  / 256.f;
    constexpr float K0 = 127.5f * 65.738f  / 256.f
                       + 127.5f * 129.057f / 256.f
                       + 127.5f * 25.064f  / 256.f + 16.f;
    return fmaf(r, W0, fmaf(g, W1, fmaf(b, W2, K0)));
}

// Streaming SSIM, one thread per output column, 32-row strip per block,
// wave-private LDS (no barriers in the row loop; one compiler fence per
// row step). waves_per_eu(4,4): VGPR budget exactly 128, all 4 blocks/CU
// co-resident (grid = 1024 blocks = 4/CU, one generation).
__global__ __launch_bounds__(256)
__attribute__((amdgpu_waves_per_eu(4, 4)))
void ssim_stream_kernel(
    const float* __restrict__ img1, const float* __restrict__ img2,
    double* __restrict__ acc_out, GW wv)
{
    __shared__ float4 sbuf[2][4][WPAD];     // parity x wave x column
    __shared__ double wsum[4];

    const int t    = threadIdx.x;
    const int lane = t & 63;
    const int wvid = t >> 6;
    const int cw = blockIdx.x * 256 + wvid * 64;  // wave's first column
    const int ox = cw + lane;                     // owned output column
    const int r0 = blockIdx.y * STRIP;
    const int b  = blockIdx.z;

    const bool colok = (ox < OUTD);
    const bool halo  = (lane < 10) && ((cw + 64 + lane) < W);
    const size_t imgbase = (size_t)b * (H * W * 3) + (size_t)r0 * (W * 3);
    const int colA = (cw + lane) * 3;             // main col (always < W)
    const int colB = (cw + 64 + lane) * 3;        // halo col

    // Raw RGB pipeline registers: c* = row iy+1 (ready), n* = row iy+2 (in flight)
    float cA0, cA1, cA2, cB0, cB1, cB2, cC0, cC1, cC2, cD0, cD1, cD2;
    float nA0, nA1, nA2, nB0, nB1, nB2, nC0, nC1, nC2, nD0, nD1, nD2;

// Issue raw loads for strip row IY into 12 named registers (NO conversion
// here — keeping load->use distance at one full row step).
#define LOAD_RAW(IY, A0,A1,A2, B0,B1,B2, C0,C1v,C2v, D0,D1,D2)            \
    {                                                                     \
        A0=A1=A2=B0=B1=B2=C0=C1v=C2v=D0=D1=D2 = 0.f;                      \
        if ((IY) < INROWS && (r0 + (IY)) < H) {                           \
            const float* _q1 = img1 + imgbase + (size_t)((IY) * (W * 3)); \
            const float* _q2 = img2 + imgbase + (size_t)((IY) * (W * 3)); \
            const F3 _pa = *reinterpret_cast<const F3*>(_q1 + colA);      \
            const F3 _pb = *reinterpret_cast<const F3*>(_q2 + colA);      \
            A0 = _pa.x; A1 = _pa.y; A2 = _pa.z;                           \
            B0 = _pb.x; B1 = _pb.y; B2 = _pb.z;                           \
            if (halo) {                                                   \
                const F3 _pc = *reinterpret_cast<const F3*>(_q1 + colB);  \
                const F3 _pd = *reinterpret_cast<const F3*>(_q2 + colB);  \
                C0  = _pc.x; C1v = _pc.y; C2v = _pc.z;                    \
                D0  = _pd.x; D1  = _pd.y; D2  = _pd.z;                    \
            }                                                             \
        }                                                                 \
    }

// Convert current raw regs (row IY) to (a, c, a^2+c^2, a*c) and store ONE
// float4 per column to LDS parity IY&1. Squares/cross computed once here.
#define STORE_ROW(IY)                                                     \
    {                                                                     \
        const int _p = (IY) & 1;                                          \
        {                                                                 \
            const float _a = luma3(cA0, cA1, cA2);                        \
            const float _c = luma3(cB0, cB1, cB2);                        \
            sbuf[_p][wvid][lane] =                                        \
                make_float4(_a, _c, fmaf(_a, _a, _c * _c), _a * _c);      \
        }                                                                 \
        if (lane < 10) {                                                  \
            const float _a = luma3(cC0, cC1, cC2);                        \
            const float _c = luma3(cD0, cD1, cD2);                        \
            sbuf[_p][wvid][64 + lane] =                                   \
                make_float4(_a, _c, fmaf(_a, _a, _c * _c), _a * _c);      \
        }                                                                 \
    }

#define ROTATE_RAW()                                                      \
    {                                                                     \
        cA0 = nA0; cA1 = nA1; cA2 = nA2; cB0 = nB0; cB1 = nB1; cB2 = nB2; \
        cC0 = nC0; cC1 = nC1; cC2 = nC2; cD0 = nD0; cD1 = nD1; cD2 = nD2; \
    }

// One row step: prefetch raw row IY+2; convert+store row IY+1; h-conv row
// IY from LDS into H0..H3. ONE fence at the top: all DS ops of the
// previous step are emitted before all DS ops of this step (covers both
// cross-step hazard directions); within the step, stores (parity ~rb)
// and reads (parity rb) are independent — scheduler is free.
// h-conv tap = one ds_read_b128 (contiguous per-lane) + 4 FMA.
#define ROW_STEP(IY, H0, H1, H2, H3)                                      \
    {                                                                     \
        LDS_FENCE();                                                      \
        LOAD_RAW((IY) + 2, nA0,nA1,nA2, nB0,nB1,nB2,                      \
                           nC0,nC1,nC2, nD0,nD1,nD2);                     \
        STORE_ROW((IY) + 1);                                              \
        ROTATE_RAW();                                                     \
        {                                                                 \
            const int _rb = (IY) & 1;                                     \
            float _h0 = 0.f, _h1 = 0.f, _h2 = 0.f, _h3 = 0.f;             \
            _Pragma("unroll")                                             \
            for (int _k = 0; _k < WS; ++_k) {                             \
                const float _gk = wv.g[_k];                               \
                const float4 _v = sbuf[_rb][wvid][lane + _k];             \
                _h0 = fmaf(_gk, _v.x, _h0);                               \
                _h1 = fmaf(_gk, _v.y, _h1);                               \
                _h2 = fmaf(_gk, _v.z, _h2);                               \
                _h3 = fmaf(_gk, _v.w, _h3);                               \
            }                                                             \
            H0 = _h0; H1 = _h1; H2 = _h2; H3 = _h3;                       \
        }                                                                 \
    }

    // Register ring: slot s holds h-conv of input row r with r % 11 == s.
    // Zero-init ALL slots — no undef values anywhere, ever.
    float rm1[WS], rm2[WS], rq[WS], rx[WS];
    #pragma unroll
    for (int s = 0; s < WS; ++s) {
        rm1[s] = 0.f; rm2[s] = 0.f; rq[s] = 0.f; rx[s] = 0.f;
    }

    // Prologue: raw row 0 -> c; raw row 1 -> n (in flight); luma row 0 -> LDS.
    LOAD_RAW(0, cA0,cA1,cA2, cB0,cB1,cB2, cC0,cC1,cC2, cD0,cD1,cD2);
    LOAD_RAW(1, nA0,nA1,nA2, nB0,nB1,nB2, nC0,nC1,nC2, nD0,nD1,nD2);
    STORE_ROW(0);                       // one-time stall on row-0 loads
    ROTATE_RAW();                       // c = raw row 1

    // Fill ring with input rows 0..9 (slots 0..9).
    #pragma unroll
    for (int j = 0; j < 10; ++j)
        ROW_STEP(j, rm1[j], rm2[j], rq[j], rx[j]);

    float local = 0.f;

// Output row OY (JM == OY % 11, compile-time): insert row OY+10 at slot
// (JM+10)%11, then vertical 11-tap conv over slots (JM+k)%11 and SSIM.
#define DO_ROW(OY, JM)                                                    \
    {                                                                     \
        ROW_STEP((OY) + 10,                                               \
                 rm1[((JM) + 10) % WS], rm2[((JM) + 10) % WS],            \
                 rq[((JM) + 10) % WS],  rx[((JM) + 10) % WS]);            \
        float _mu1 = 0.f, _mu2 = 0.f, _eq = 0.f, _ex = 0.f;               \
        _Pragma("unroll")                                                 \
        for (int _k = 0; _k < WS; ++_k) {                                 \
            const float _gk = wv.g[_k];                                   \
            const int _s = ((JM) + _k) % WS;                              \
            _mu1 = fmaf(_gk, rm1[_s], _mu1);                              \
            _mu2 = fmaf(_gk, rm2[_s], _mu2);                              \
            _eq  = fmaf(_gk, rq[_s],  _eq);                               \
            _ex  = fmaf(_gk, rx[_s],  _ex);                               \
        }                                                                 \
        if (colok && (r0 + (OY)) < OUTD) {                                \
            const float _m1s = _mu1 * _mu1;                               \
            const float _m2s = _mu2 * _mu2;                               \
            const float _m12 = _mu1 * _mu2;                               \
            const float _num = (2.f * _m12 + C1F) *                       \
                               (2.f * (_ex - _m12) + C2F);                \
            const float _den = (_m1s + _m2s + C1F) *                      \
                               ((_eq - _m1s - _m2s) + C2F);               \
            local = fmaf(_num, __builtin_amdgcn_rcpf(_den), local);       \
        }                                                                 \
    }

    // Output rows 0..21: ROLLED 2-chunk loop (backedge helps the
    // allocator meet the 128 budget); rows 22..31 unrolled tail.
    // Ring indices stay compile-time (JM=j).
    #pragma unroll 1
    for (int c = 0; c < 2; ++c) {
        const int base = c * 11;
        #pragma unroll
        for (int j = 0; j < 11; ++j)
            DO_ROW(base + j, j);
    }
    #pragma unroll
    for (int j = 0; j < 10; ++j)
        DO_ROW(22 + j, j);

    // Block reduction: wave shuffle (f32 tree) -> LDS (double) -> one atomic.
    for (int off = 32; off > 0; off >>= 1)
        local += __shfl_down(local, off, 64);
    if (lane == 0) wsum[wvid] = (double)local;
    __syncthreads();
    if (t == 0) {
        const double s = wsum[0] + wsum[1] + wsum[2] + wsum[3];
        atomicAdd(acc_out, s);
    }
}

__global__ void ssim_finalize_kernel(const double* __restrict__ acc,
                                     float* __restrict__ out)
{
    out[0] = (float)(acc[0] / N_OUT_TOTAL);
}

extern "C" void kernel_launch(void* const* d_in, const int* in_sizes, int n_in,
                              void* d_out, int out_size, void* d_ws, size_t ws_size,
                              hipStream_t stream) {
    const float* img1 = (const float*)d_in[0];
    const float* img2 = (const float*)d_in[1];
    float* out = (float*)d_out;
    double* acc = (double*)d_ws;

    // Gaussian window, computed exactly as the numpy reference (float32 ops)
    GW w;
    {
        float g[WS];
        float s = 0.f;
        for (int i = 0; i < WS; ++i) {
            const float x = (float)(i - WS / 2);
            g[i] = expf(-(x * x) / (2.f * 1.5f * 1.5f));
            s += g[i];
        }
        for (int i = 0; i < WS; ++i) w.g[i] = g[i] / s;
    }

    hipMemsetAsync(d_ws, 0, sizeof(double), stream);

    dim3 grid(2, (OUTD + STRIP - 1) / STRIP, BATCH);   // 2 x 16 x 32 = 1024 blocks
    ssim_stream_kernel<<<grid, 256, 0, stream>>>(img1, img2, acc, w);
    ssim_finalize_kernel<<<1, 1, 0, stream>>>(acc, out);
}

// Round 7
// 247.421 us; speedup vs baseline: 1.4948x; 1.4948x over previous
//
#include <hip/hip_runtime.h>
#include <math.h>

// Problem constants
#define BATCH 32
#define H 512
#define W 512
#define OUTD 502          // 512 - 11 + 1
#define WS 11
#define STRIP 32          // output rows per block
#define INROWS 42         // STRIP + WS - 1 input rows per strip
#define WPAD 80           // per-wave LDS row width: 64 cols + 10 halo + pad

#define C1F 6.5025f       // (0.01*255)^2
#define C2F 58.5225f      // (0.03*255)^2
#define N_OUT_TOTAL 8064128.0   // 32 * 502 * 502

struct GW { float g[WS]; };
struct F3 { float x, y, z; };   // 12-byte RGB pixel load

// ROUND-15: isolating the register-pressure variable.
// Occupancy-knob post-mortem (rounds 12/14): BOTH launch_bounds(256,4)
// and amdgpu_waves_per_eu(4,4) drive the allocator to 64 VGPR + 300-420
// MB scratch spill. Any explicit occupancy constraint = spill-to-the-
// bottom on this toolchain. DEAD LEVER; occupancy must come from
// naturally low pressure.
// Pressure matrix: {no-fence, scalar-LDS, rolled} = 124 VGPR (round 8);
// {fence, float4-LDS, unrolled} = 236 (r11); {fence, float4, rolled} =
// 224 (r13). Rolled/unrolled ~ no effect. Culprit is fence XOR float4
// payload — this round is the clean A/B: fence + SCALAR payload +
// rolled. Mechanism suspicion: the h-conv's 11 ds_read_b128 (4-reg
// values, 44 regs in flight) vs scalar b32's 1-reg granularity.
// Kernel = round-8 shape (124 VGPR, 121 us config) + exactly:
//   (i)  LDS_FENCE per ROW_STEP — the twice-proven correctness fix for
//        the wave-private-LDS compiler-reorder race (absmax 0.0 in
//        rounds 11-14; HW runs DS ops in wave order, the fence makes
//        emitted order = program order across row steps).
//   (ii) register-neutral math diet only: luma as 3 FMAs (affine folded
//        into weights), SSIM divide via v_rcp_f32 (den >= C1F*C2F > 0),
//        f32 per-thread accumulator (double only at block level).
// Float4 LDS payload REVERTED to scalar [2][4][2][WPAD]: h-conv tap =
// 2x ds_read_b32 + 7 VALU (squares recomputed per tap — the VALU cost
// is the price of the 1-reg read granularity until the A/B says
// otherwise).

#define LDS_FENCE() asm volatile("" ::: "memory")

__device__ __forceinline__ float luma3(float r, float g, float b) {
    // y = ((x+1)*127.5) dot w / 256 + 16  ==  x dot W + K, all f32-folded
    constexpr float W0 = 127.5f * 65.738f  / 256.f;
    constexpr float W1 = 127.5f * 129.057f / 256.f;
    constexpr float W2 = 127.5f * 25.064f  / 256.f;
    constexpr float K0 = 127.5f * 65.738f  / 256.f
                       + 127.5f * 129.057f / 256.f
                       + 127.5f * 25.064f  / 256.f + 16.f;
    return fmaf(r, W0, fmaf(g, W1, fmaf(b, W2, K0)));
}

// Streaming SSIM, one thread per output column, 32-row strip per block,
// wave-private LDS (no barriers in the row loop; one compiler fence per
// row step).
__global__ __launch_bounds__(256) void ssim_stream_kernel(
    const float* __restrict__ img1, const float* __restrict__ img2,
    double* __restrict__ acc_out, GW wv)
{
    __shared__ float sbuf[2][4][2][WPAD];   // parity x wave x img x width
    __shared__ double wsum[4];

    const int t    = threadIdx.x;
    const int lane = t & 63;
    const int wvid = t >> 6;
    const int cw = blockIdx.x * 256 + wvid * 64;  // wave's first column
    const int ox = cw + lane;                     // owned output column
    const int r0 = blockIdx.y * STRIP;
    const int b  = blockIdx.z;

    const bool colok = (ox < OUTD);
    const bool halo  = (lane < 10) && ((cw + 64 + lane) < W);
    const size_t imgbase = (size_t)b * (H * W * 3) + (size_t)r0 * (W * 3);
    const int colA = (cw + lane) * 3;             // main col (always < W)
    const int colB = (cw + 64 + lane) * 3;        // halo col

    // Raw RGB pipeline registers: c* = row iy+1 (ready), n* = row iy+2 (in flight)
    float cA0, cA1, cA2, cB0, cB1, cB2, cC0, cC1, cC2, cD0, cD1, cD2;
    float nA0, nA1, nA2, nB0, nB1, nB2, nC0, nC1, nC2, nD0, nD1, nD2;

// Issue raw loads for strip row IY into 12 named registers (NO conversion
// here — keeping load->use distance at one full row step).
#define LOAD_RAW(IY, A0,A1,A2, B0,B1,B2, C0,C1v,C2v, D0,D1,D2)            \
    {                                                                     \
        A0=A1=A2=B0=B1=B2=C0=C1v=C2v=D0=D1=D2 = 0.f;                      \
        if ((IY) < INROWS && (r0 + (IY)) < H) {                           \
            const float* _q1 = img1 + imgbase + (size_t)((IY) * (W * 3)); \
            const float* _q2 = img2 + imgbase + (size_t)((IY) * (W * 3)); \
            const F3 _pa = *reinterpret_cast<const F3*>(_q1 + colA);      \
            const F3 _pb = *reinterpret_cast<const F3*>(_q2 + colA);      \
            A0 = _pa.x; A1 = _pa.y; A2 = _pa.z;                           \
            B0 = _pb.x; B1 = _pb.y; B2 = _pb.z;                           \
            if (halo) {                                                   \
                const F3 _pc = *reinterpret_cast<const F3*>(_q1 + colB);  \
                const F3 _pd = *reinterpret_cast<const F3*>(_q2 + colB);  \
                C0  = _pc.x; C1v = _pc.y; C2v = _pc.z;                    \
                D0  = _pd.x; D1  = _pd.y; D2  = _pd.z;                    \
            }                                                             \
        }                                                                 \
    }

// Convert current raw regs (row IY) to luma and store to LDS parity IY&1.
// Scalar b32 stores (round-8 layout — 1-reg granularity for the allocator).
#define STORE_ROW(IY)                                                     \
    {                                                                     \
        const int _p = (IY) & 1;                                          \
        sbuf[_p][wvid][0][lane] = luma3(cA0, cA1, cA2);                   \
        sbuf[_p][wvid][1][lane] = luma3(cB0, cB1, cB2);                   \
        if (lane < 10) {                                                  \
            sbuf[_p][wvid][0][64 + lane] = luma3(cC0, cC1, cC2);          \
            sbuf[_p][wvid][1][64 + lane] = luma3(cD0, cD1, cD2);          \
        }                                                                 \
    }

#define ROTATE_RAW()                                                      \
    {                                                                     \
        cA0 = nA0; cA1 = nA1; cA2 = nA2; cB0 = nB0; cB1 = nB1; cB2 = nB2; \
        cC0 = nC0; cC1 = nC1; cC2 = nC2; cD0 = nD0; cD1 = nD1; cD2 = nD2; \
    }

// One row step: prefetch raw row IY+2; convert+store row IY+1; h-conv row
// IY from LDS into H0..H3. ONE fence at the top: all DS ops of the
// previous step are emitted before all DS ops of this step (covers both
// cross-step hazard directions); within the step, stores (parity ~rb)
// and reads (parity rb) touch opposite buffers — scheduler is free.
#define ROW_STEP(IY, H0, H1, H2, H3)                                      \
    {                                                                     \
        LDS_FENCE();                                                      \
        LOAD_RAW((IY) + 2, nA0,nA1,nA2, nB0,nB1,nB2,                      \
                           nC0,nC1,nC2, nD0,nD1,nD2);                     \
        STORE_ROW((IY) + 1);                                              \
        ROTATE_RAW();                                                     \
        {                                                                 \
            const int _rb = (IY) & 1;                                     \
            float _h0 = 0.f, _h1 = 0.f, _h2 = 0.f, _h3 = 0.f;             \
            _Pragma("unroll")                                             \
            for (int _k = 0; _k < WS; ++_k) {                             \
                const float _gk = wv.g[_k];                               \
                const float _a = sbuf[_rb][wvid][0][lane + _k];           \
                const float _c = sbuf[_rb][wvid][1][lane + _k];           \
                _h0 = fmaf(_gk, _a, _h0);                                 \
                _h1 = fmaf(_gk, _c, _h1);                                 \
                _h2 = fmaf(_gk, fmaf(_a, _a, _c * _c), _h2);              \
                _h3 = fmaf(_gk, _a * _c, _h3);                            \
            }                                                             \
            H0 = _h0; H1 = _h1; H2 = _h2; H3 = _h3;                       \
        }                                                                 \
    }

    // Register ring: slot s holds h-conv of input row r with r % 11 == s.
    // Zero-init ALL slots — no undef values anywhere, ever.
    float rm1[WS], rm2[WS], rq[WS], rx[WS];
    #pragma unroll
    for (int s = 0; s < WS; ++s) {
        rm1[s] = 0.f; rm2[s] = 0.f; rq[s] = 0.f; rx[s] = 0.f;
    }

    // Prologue: raw row 0 -> c; raw row 1 -> n (in flight); luma row 0 -> LDS.
    LOAD_RAW(0, cA0,cA1,cA2, cB0,cB1,cB2, cC0,cC1,cC2, cD0,cD1,cD2);
    LOAD_RAW(1, nA0,nA1,nA2, nB0,nB1,nB2, nC0,nC1,nC2, nD0,nD1,nD2);
    STORE_ROW(0);                       // one-time stall on row-0 loads
    ROTATE_RAW();                       // c = raw row 1

    // Fill ring with input rows 0..9 (slots 0..9).
    #pragma unroll
    for (int j = 0; j < 10; ++j)
        ROW_STEP(j, rm1[j], rm2[j], rq[j], rx[j]);

    float local = 0.f;

// Output row OY (JM == OY % 11, compile-time): insert row OY+10 at slot
// (JM+10)%11, then vertical 11-tap conv over slots (JM+k)%11 and SSIM.
#define DO_ROW(OY, JM)                                                    \
    {                                                                     \
        ROW_STEP((OY) + 10,                                               \
                 rm1[((JM) + 10) % WS], rm2[((JM) + 10) % WS],            \
                 rq[((JM) + 10) % WS],  rx[((JM) + 10) % WS]);            \
        float _mu1 = 0.f, _mu2 = 0.f, _eq = 0.f, _ex = 0.f;               \
        _Pragma("unroll")                                                 \
        for (int _k = 0; _k < WS; ++_k) {                                 \
            const float _gk = wv.g[_k];                                   \
            const int _s = ((JM) + _k) % WS;                              \
            _mu1 = fmaf(_gk, rm1[_s], _mu1);                              \
            _mu2 = fmaf(_gk, rm2[_s], _mu2);                              \
            _eq  = fmaf(_gk, rq[_s],  _eq);                               \
            _ex  = fmaf(_gk, rx[_s],  _ex);                               \
        }                                                                 \
        if (colok && (r0 + (OY)) < OUTD) {                                \
            const float _m1s = _mu1 * _mu1;                               \
            const float _m2s = _mu2 * _mu2;                               \
            const float _m12 = _mu1 * _mu2;                               \
            const float _num = (2.f * _m12 + C1F) *                       \
                               (2.f * (_ex - _m12) + C2F);                \
            const float _den = (_m1s + _m2s + C1F) *                      \
                               ((_eq - _m1s - _m2s) + C2F);               \
            local = fmaf(_num, __builtin_amdgcn_rcpf(_den), local);       \
        }                                                                 \
    }

    // Output rows 0..21: ROLLED 2-chunk loop; rows 22..31 unrolled tail.
    // Ring indices stay compile-time (JM=j).
    #pragma unroll 1
    for (int c = 0; c < 2; ++c) {
        const int base = c * 11;
        #pragma unroll
        for (int j = 0; j < 11; ++j)
            DO_ROW(base + j, j);
    }
    #pragma unroll
    for (int j = 0; j < 10; ++j)
        DO_ROW(22 + j, j);

    // Block reduction: wave shuffle (f32 tree) -> LDS (double) -> one atomic.
    for (int off = 32; off > 0; off >>= 1)
        local += __shfl_down(local, off, 64);
    if (lane == 0) wsum[wvid] = (double)local;
    __syncthreads();
    if (t == 0) {
        const double s = wsum[0] + wsum[1] + wsum[2] + wsum[3];
        atomicAdd(acc_out, s);
    }
}

__global__ void ssim_finalize_kernel(const double* __restrict__ acc,
                                     float* __restrict__ out)
{
    out[0] = (float)(acc[0] / N_OUT_TOTAL);
}

extern "C" void kernel_launch(void* const* d_in, const int* in_sizes, int n_in,
                              void* d_out, int out_size, void* d_ws, size_t ws_size,
                              hipStream_t stream) {
    const float* img1 = (const float*)d_in[0];
    const float* img2 = (const float*)d_in[1];
    float* out = (float*)d_out;
    double* acc = (double*)d_ws;

    // Gaussian window, computed exactly as the numpy reference (float32 ops)
    GW w;
    {
        float g[WS];
        float s = 0.f;
        for (int i = 0; i < WS; ++i) {
            const float x = (float)(i - WS / 2);
            g[i] = expf(-(x * x) / (2.f * 1.5f * 1.5f));
            s += g[i];
        }
        for (int i = 0; i < WS; ++i) w.g[i] = g[i] / s;
    }

    hipMemsetAsync(d_ws, 0, sizeof(double), stream);

    dim3 grid(2, (OUTD + STRIP - 1) / STRIP, BATCH);   // 2 x 16 x 32 = 1024 blocks
    ssim_stream_kernel<<<grid, 256, 0, stream>>>(img1, img2, acc, w);
    ssim_finalize_kernel<<<1, 1, 0, stream>>>(acc, out);
}